// Round 2
// baseline (545.812 us; speedup 1.0000x reference)
//
#include <hip/hip_runtime.h>
#include <stdint.h>

// DomainAttentionLayer: out = softmax((x Wq^T + bq)(dx Wk^T + bk)^T / sqrt(D)) (dx Wv^T + bv)
// N = M = 8192, D = 512, fp32 in/out; internal compute bf16 MFMA.
//
// Pipeline:
//   0) prep_w    : W fp32 -> bf16 (once, so qkv_proj doesn't re-convert per block)
//   1) qkv_proj  : bf16 GEMMs, bias fused; Q pre-scaled by log2(e)/sqrt(D); V stored VT[D][M]
//   2) flash_attn: fused online-softmax attention, split-m x SPLITS partials
//                  (D-split PV: V-frags read once per CU, P shared via LDS)
//   3) combine   : exact log-sum-exp merge of partials -> fp32 out

#define DEV __device__ __forceinline__

typedef short short8 __attribute__((ext_vector_type(8)));     // 8 bf16 (4 VGPRs) MFMA frag
typedef float floatx4 __attribute__((ext_vector_type(4)));    // MFMA accum
typedef unsigned int uintx4 __attribute__((ext_vector_type(4)));
typedef unsigned short ushortx4 __attribute__((ext_vector_type(4)));

constexpr int NN = 8192;
constexpr int MM = 8192;
constexpr int DD = 512;
constexpr float SCALE2 = 0.0637587160f;         // log2(e) / sqrt(512), folded into Q

#define NEG_INF (-__builtin_inff())

#if defined(__has_builtin)
#if __has_builtin(__builtin_amdgcn_exp2f)
#define EXP2F(x) __builtin_amdgcn_exp2f(x)
#else
#define EXP2F(x) exp2f(x)
#endif
#else
#define EXP2F(x) exp2f(x)
#endif

DEV unsigned short f2bf(float f) {              // RNE fp32 -> bf16 bits
  unsigned u = __builtin_bit_cast(unsigned, f);
  return (unsigned short)((u + 0x7FFFu + ((u >> 16) & 1u)) >> 16);
}
DEV float bf2f(unsigned short h) {
  unsigned u = ((unsigned)h) << 16;
  return __builtin_bit_cast(float, u);
}

// TBAA-safe vector ld/st (memcpy compiles to single b128/b64 with assumed alignment)
DEV short8 ld_s8(const void* p) {
  short8 v; __builtin_memcpy(&v, __builtin_assume_aligned(p, 16), 16); return v;
}
DEV uintx4 ld_u4(const void* p) {
  uintx4 v; __builtin_memcpy(&v, __builtin_assume_aligned(p, 16), 16); return v;
}
DEV void st_u4(void* p, uintx4 v) {
  __builtin_memcpy(__builtin_assume_aligned(p, 16), &v, 16);
}
DEV void st_us4(void* p, ushortx4 v) {
  __builtin_memcpy(__builtin_assume_aligned(p, 8), &v, 8);
}
DEV float4 ld_f4(const void* p) {
  float4 v; __builtin_memcpy(&v, __builtin_assume_aligned(p, 16), 16); return v;
}

DEV void async_lds16(const void* g, const void* l) {  // global -> LDS DMA, 16B/lane
  __builtin_amdgcn_global_load_lds(
      (const __attribute__((address_space(1))) unsigned int*)g,
      (__attribute__((address_space(3))) unsigned int*)l, 16, 0, 0);
}

// ---------------------------------------------------------------------------
// Kernel 0: W fp32 -> bf16, once. grid (128, 1, 3), block 256, 8 elems/thread.
// ---------------------------------------------------------------------------
__global__ void prep_w(const float* __restrict__ Wq, const float* __restrict__ Wk,
                       const float* __restrict__ Wv, unsigned short* __restrict__ Wb) {
  const int z = blockIdx.z;
  const float* src = (z == 0) ? Wq : (z == 1) ? Wk : Wv;
  unsigned short* dst = Wb + (size_t)z * DD * DD;
  size_t idx = ((size_t)blockIdx.x * 256 + threadIdx.x) * 8;
  float4 a = ld_f4(src + idx);
  float4 b = ld_f4(src + idx + 4);
  ushortx4 lo = {f2bf(a.x), f2bf(a.y), f2bf(a.z), f2bf(a.w)};
  ushortx4 hi = {f2bf(b.x), f2bf(b.y), f2bf(b.z), f2bf(b.w)};
  st_us4(dst + idx, lo);
  st_us4(dst + idx + 4, hi);
}

// ---------------------------------------------------------------------------
// Kernel 1: QKV projection. grid (128, 2, 3), block 256. Tile 64 rows x 256 cols,
// BK=64. LDS xor-swizzled (chunk ^= row&7) -> conflict-free b128 frag reads.
// z=0: Q (scaled by SCALE2) -> Qb[N][D]; z=1: K -> Kb[M][D]; z=2: V -> VTb[D][M].
// ---------------------------------------------------------------------------
__global__ __launch_bounds__(256, 2)
void qkv_proj(const float* __restrict__ x, const float* __restrict__ dx,
              const unsigned short* __restrict__ Wb,
              const float* __restrict__ bq, const float* __restrict__ bk,
              const float* __restrict__ bv,
              unsigned short* __restrict__ Qb, unsigned short* __restrict__ Kb,
              unsigned short* __restrict__ VTb) {
  const int z = blockIdx.z;
  const float* A = (z == 0) ? x : dx;
  const unsigned short* W = Wb + (size_t)z * DD * DD;
  const float* bias = (z == 0) ? bq : (z == 1) ? bk : bv;

  const int r0 = blockIdx.x * 64;
  const int c0 = blockIdx.y * 256;
  const int tid = threadIdx.x;
  const int lane = tid & 63;
  const int wave = tid >> 6;
  const int lr = lane & 15;
  const int quad = lane >> 4;

  __shared__ __align__(16) unsigned short As[64 * 64];   //  8 KB
  __shared__ __align__(16) unsigned short Ws[256 * 64];  // 32 KB

  floatx4 o[16];
#pragma unroll
  for (int i = 0; i < 16; ++i) o[i] = {0.f, 0.f, 0.f, 0.f};

  for (int k0 = 0; k0 < DD; k0 += 64) {
    // stage A tile (fp32 -> bf16): 64 rows x 64 k, 4 float4 per thread
#pragma unroll
    for (int i = 0; i < 4; ++i) {
      int idx = i * 256 + tid;
      int r = idx >> 4, c4 = idx & 15;
      float4 v = ld_f4(A + (size_t)(r0 + r) * DD + k0 + c4 * 4);
      ushortx4 pk = {f2bf(v.x), f2bf(v.y), f2bf(v.z), f2bf(v.w)};
      st_us4(&As[r * 64 + (((c4 >> 1) ^ (r & 7)) * 8) + (c4 & 1) * 4], pk);
    }
    // stage W tile (bf16, no convert): 256 rows x 64 k, 8 x 16B per thread
#pragma unroll
    for (int i = 0; i < 8; ++i) {
      int idx = i * 256 + tid;
      int r = idx >> 3, c = idx & 7;
      uintx4 v = ld_u4(W + (size_t)(c0 + r) * DD + k0 + c * 8);
      st_u4(&Ws[r * 64 + ((c ^ (r & 7)) * 8)], v);
    }
    __syncthreads();

    short8 a[2];
#pragma unroll
    for (int ks = 0; ks < 2; ++ks)
      a[ks] = ld_s8(&As[(wave * 16 + lr) * 64 + (((ks * 4 + quad) ^ (lr & 7)) * 8)]);
#pragma unroll
    for (int ct = 0; ct < 16; ++ct) {
#pragma unroll
      for (int ks = 0; ks < 2; ++ks) {
        short8 b = ld_s8(&Ws[(ct * 16 + lr) * 64 + (((ks * 4 + quad) ^ (lr & 7)) * 8)]);
        o[ct] = __builtin_amdgcn_mfma_f32_16x16x32_bf16(a[ks], b, o[ct], 0, 0, 0);
      }
    }
    __syncthreads();
  }

  // epilogue: bias (+Q scale), store. C layout: col = lr, row = quad*4 + reg.
#pragma unroll
  for (int ct = 0; ct < 16; ++ct) {
    int col = c0 + ct * 16 + lr;
    float bv_ = bias[col];
    int rowb = r0 + wave * 16 + quad * 4;
    if (z == 2) {  // VT[col][row], 4 consecutive rows -> 8B store
      ushortx4 pk = {f2bf(o[ct][0] + bv_), f2bf(o[ct][1] + bv_),
                     f2bf(o[ct][2] + bv_), f2bf(o[ct][3] + bv_)};
      st_us4(VTb + (size_t)col * MM + rowb, pk);
    } else {
      unsigned short* Outp = (z == 0) ? Qb : Kb;
      float sc = (z == 0) ? SCALE2 : 1.f;
#pragma unroll
      for (int r = 0; r < 4; ++r)
        Outp[(size_t)(rowb + r) * DD + col] = f2bf((o[ct][r] + bv_) * sc);
    }
  }
}

// ---------------------------------------------------------------------------
// Kernel 2: flash attention. grid (N/64, SPLITS_), block 256 (4 waves), 2 blocks/CU.
// S phase: wave w owns q-rows [16w,16w+16) (softmax state wave-private).
// PV phase (D-split): wave w computes O[all 64 rows][cols 128w..128w+128) --
// V-frags read once per CU; P (64x64) and alphas shared via LDS.
// LDS 76,544 B -> 2 blocks/CU.
// ---------------------------------------------------------------------------
template <int SPLITS_>
__global__ __launch_bounds__(256, 2)
void flash_attn(const unsigned short* __restrict__ Qb,
                const unsigned short* __restrict__ Kb,
                const unsigned short* __restrict__ VTb,
                unsigned short* __restrict__ Opart,
                float* __restrict__ Mpart, float* __restrict__ Lpart) {
  constexpr int MT = MM / SPLITS_;
  constexpr int ITERS = MT / 64;
  const int n0 = blockIdx.x * 64;
  const int split = blockIdx.y;
  const int m_begin = split * MT;

  const int tid = threadIdx.x;
  const int lane = tid & 63;
  const int wave = tid >> 6;
  const int lr = lane & 15;
  const int quad = lane >> 4;

  // sKV: K phase rows stride 520 us (1040B, DMA row + 16B pad, conflict-free);
  // VT phase rows stride 64 us with chunk^=(row&7) xor swizzle (conflict-free).
  __shared__ __align__(16) unsigned short sKV[33280];      // 66,560 B
  __shared__ __align__(16) unsigned short sP[64 * 76];     //  9,728 B (stride 76: 2-way only)
  __shared__ float sAlpha[64];                             //    256 B

  // resident Q fragments: wave's 16 rows x 512 k (64 VGPRs), pre-scaled by SCALE2
  short8 qf[16];
  {
    const unsigned short* qptr = Qb + (size_t)(n0 + wave * 16 + lr) * DD + quad * 8;
#pragma unroll
    for (int ks = 0; ks < 16; ++ks) qf[ks] = ld_s8(qptr + ks * 32);
  }

  floatx4 o[32];  // [rt][ct] -> rt*8+ct : O rows rt*16+quad*4+reg, col wave*128+ct*16+lr
#pragma unroll
  for (int i = 0; i < 32; ++i) o[i] = {0.f, 0.f, 0.f, 0.f};
  float mrow[4] = {NEG_INF, NEG_INF, NEG_INF, NEG_INF};
  float lrow[4] = {0.f, 0.f, 0.f, 0.f};

  for (int it = 0; it < ITERS; ++it) {
    const int m0 = m_begin + it * 64;

    // ---- stage K tile: one DMA per row (64 lanes x 16B = exactly 1024B row)
#pragma unroll
    for (int i = 0; i < 16; ++i) {
      const int r = wave * 16 + i;  // wave-uniform LDS dest
      async_lds16(Kb + (size_t)(m0 + r) * DD + lane * 8, &sKV[r * 520]);
    }
    __syncthreads();  // drains vmcnt -> K visible

    // ---- S = Q K^T (wave: its 16 rows x 64 cols), logits already in log2 units
    floatx4 s[4];
#pragma unroll
    for (int ct = 0; ct < 4; ++ct) s[ct] = {0.f, 0.f, 0.f, 0.f};
#pragma unroll
    for (int ks = 0; ks < 16; ++ks) {
      const unsigned short* kb = &sKV[ks * 32 + quad * 8];
#pragma unroll
      for (int ct = 0; ct < 4; ++ct) {
        short8 b = ld_s8(kb + (ct * 16 + lr) * 520);
        s[ct] = __builtin_amdgcn_mfma_f32_16x16x32_bf16(qf[ks], b, s[ct], 0, 0, 0);
      }
    }
    __syncthreads();  // all waves done with K region

    // ---- VT staging round 0 loads (global; latency overlaps softmax)
    uintx4 vt[8];
#pragma unroll
    for (int i = 0; i < 8; ++i) {
      int idx = i * 256 + tid;
      int r = idx >> 3, c = idx & 7;
      vt[i] = ld_u4(VTb + (size_t)r * MM + m0 + c * 8);
    }

    // ---- online softmax (rows quad*4+r, cols across the 16 lanes of the quad)
    float alpha[4];
#pragma unroll
    for (int r = 0; r < 4; ++r) {
      float mx = fmaxf(fmaxf(s[0][r], s[1][r]), fmaxf(s[2][r], s[3][r]));
      mx = fmaxf(mx, __shfl_xor(mx, 1));
      mx = fmaxf(mx, __shfl_xor(mx, 2));
      mx = fmaxf(mx, __shfl_xor(mx, 4));
      mx = fmaxf(mx, __shfl_xor(mx, 8));
      float mnew = fmaxf(mrow[r], mx);
      alpha[r] = EXP2F(mrow[r] - mnew);  // first iter: exp2(-inf) = 0
      mrow[r] = mnew;
      float rs = 0.f;
#pragma unroll
      for (int ct = 0; ct < 4; ++ct) {
        float p = EXP2F(s[ct][r] - mnew);
        s[ct][r] = p;
        rs += p;
      }
      rs += __shfl_xor(rs, 1);
      rs += __shfl_xor(rs, 2);
      rs += __shfl_xor(rs, 4);
      rs += __shfl_xor(rs, 8);
      lrow[r] = lrow[r] * alpha[r] + rs;
    }
    if (lr == 0) {
#pragma unroll
      for (int r = 0; r < 4; ++r) sAlpha[wave * 16 + quad * 4 + r] = alpha[r];
    }

    // ---- VT store round 0 (xor swizzle), then round 1 load
#pragma unroll
    for (int i = 0; i < 8; ++i) {
      int idx = i * 256 + tid;
      int r = idx >> 3, c = idx & 7;
      st_u4(&sKV[r * 64 + ((c ^ (r & 7)) * 8)], vt[i]);
    }
#pragma unroll
    for (int i = 0; i < 8; ++i) {
      int idx = (i + 8) * 256 + tid;
      int r = idx >> 3, c = idx & 7;
      vt[i] = ld_u4(VTb + (size_t)r * MM + m0 + c * 8);
    }

    // ---- P (C layout) -> shared LDS bf16 [64][76]
#pragma unroll
    for (int ct = 0; ct < 4; ++ct)
#pragma unroll
      for (int r = 0; r < 4; ++r)
        sP[(wave * 16 + quad * 4 + r) * 76 + ct * 16 + lr] = f2bf(s[ct][r]);

    // ---- VT store round 1
#pragma unroll
    for (int i = 0; i < 8; ++i) {
      int idx = (i + 8) * 256 + tid;
      int r = idx >> 3, c = idx & 7;
      st_u4(&sKV[r * 64 + ((c ^ (r & 7)) * 8)], vt[i]);
    }
    __syncthreads();  // P, alphas, VT visible

    // ---- rescale O by all-row alphas (shared)
    float af[16];
#pragma unroll
    for (int rt = 0; rt < 4; ++rt)
#pragma unroll
      for (int r = 0; r < 4; ++r) af[rt * 4 + r] = sAlpha[rt * 16 + quad * 4 + r];
    bool need = false;
#pragma unroll
    for (int i = 0; i < 16; ++i) need = need || (af[i] < 1.f);
    if (__any(need)) {
#pragma unroll
      for (int rt = 0; rt < 4; ++rt)
#pragma unroll
        for (int ct = 0; ct < 8; ++ct)
#pragma unroll
          for (int r = 0; r < 4; ++r) o[rt * 8 + ct][r] *= af[rt * 4 + r];
    }

    // ---- O += P V (D-split): A = P rows (all 64), B = V[m][dcol] for wave's 128 d-cols
    short8 pa[8];  // [rt][ks]
#pragma unroll
    for (int rt = 0; rt < 4; ++rt)
#pragma unroll
      for (int ks = 0; ks < 2; ++ks)
        pa[rt * 2 + ks] = ld_s8(&sP[(rt * 16 + lr) * 76 + ks * 32 + quad * 8]);
#pragma unroll
    for (int ct = 0; ct < 8; ++ct) {
      const int r = wave * 128 + ct * 16 + lr;  // VT LDS row = d-col
      const unsigned short* vb = &sKV[r * 64];
      const int sw = r & 7;
#pragma unroll
      for (int ks = 0; ks < 2; ++ks) {
        short8 b = ld_s8(vb + (((ks * 4 + quad) ^ sw) * 8));
#pragma unroll
        for (int rt = 0; rt < 4; ++rt)
          o[rt * 8 + ct] = __builtin_amdgcn_mfma_f32_16x16x32_bf16(pa[rt * 2 + ks], b,
                                                                   o[rt * 8 + ct], 0, 0, 0);
      }
    }
    __syncthreads();  // sKV/sP/sAlpha free for next iter
  }

  // ---- epilogue: unnormalized partials (D-split layout)
  unsigned short* op = Opart + (size_t)split * NN * DD;
#pragma unroll
  for (int rt = 0; rt < 4; ++rt)
#pragma unroll
    for (int ct = 0; ct < 8; ++ct) {
      int row = n0 + rt * 16 + quad * 4;
      int col = wave * 128 + ct * 16 + lr;
#pragma unroll
      for (int r = 0; r < 4; ++r)
        op[(size_t)(row + r) * DD + col] = f2bf(o[rt * 8 + ct][r]);
    }
  const int grow = n0 + wave * 16 + quad * 4;
  if (lr == 0) {
#pragma unroll
    for (int r = 0; r < 4; ++r) {
      Mpart[split * NN + grow + r] = mrow[r];
      Lpart[split * NN + grow + r] = lrow[r];
    }
  }
}

// ---------------------------------------------------------------------------
// Kernel 3: exact softmax merge of SPLITS partials. 8 elems/thread, b128 I/O.
// grid (N*D/2048), block 256.
// ---------------------------------------------------------------------------
template <int SPLITS_>
__global__ void combine_kernel(const unsigned short* __restrict__ Op,
                               const float* __restrict__ Mp,
                               const float* __restrict__ Lp,
                               float* __restrict__ out) {
  constexpr size_t NDv = (size_t)NN * DD;
  size_t base = ((size_t)blockIdx.x * 256 + threadIdx.x) * 8;
  int n = (int)(base >> 9);
  float mv[SPLITS_];
  float ms = NEG_INF;
#pragma unroll
  for (int s = 0; s < SPLITS_; ++s) {
    mv[s] = Mp[s * NN + n];
    ms = fmaxf(ms, mv[s]);
  }
  float num[8];
#pragma unroll
  for (int j = 0; j < 8; ++j) num[j] = 0.f;
  float den = 0.f;
#pragma unroll
  for (int s = 0; s < SPLITS_; ++s) {
    float w = EXP2F(mv[s] - ms);
    den += w * Lp[s * NN + n];
    uintx4 u = ld_u4(Op + s * NDv + base);
#pragma unroll
    for (int j = 0; j < 4; ++j) {
      num[2 * j]     += w * bf2f((unsigned short)(u[j] & 0xffffu));
      num[2 * j + 1] += w * bf2f((unsigned short)(u[j] >> 16));
    }
  }
  float inv = 1.f / den;
  float4 o0 = {num[0] * inv, num[1] * inv, num[2] * inv, num[3] * inv};
  float4 o1 = {num[4] * inv, num[5] * inv, num[6] * inv, num[7] * inv};
  __builtin_memcpy(__builtin_assume_aligned(out + base, 16), &o0, 16);
  __builtin_memcpy(__builtin_assume_aligned(out + base + 4, 16), &o1, 16);
}

// ---------------------------------------------------------------------------
extern "C" void kernel_launch(void* const* d_in, const int* in_sizes, int n_in,
                              void* d_out, int out_size, void* d_ws, size_t ws_size,
                              hipStream_t stream) {
  const float* x  = (const float*)d_in[0];
  const float* dx = (const float*)d_in[1];
  const float* Wq = (const float*)d_in[2];
  const float* bq = (const float*)d_in[3];
  const float* Wk = (const float*)d_in[4];
  const float* bk = (const float*)d_in[5];
  const float* Wv = (const float*)d_in[6];
  const float* bv = (const float*)d_in[7];
  float* out = (float*)d_out;

  const size_t ND = (size_t)NN * DD;          // 4,194,304
  const size_t WBE = (size_t)3 * DD * DD;     //   786,432
  unsigned short* Qb  = (unsigned short*)d_ws;     // bf16, ND (pre-scaled)
  unsigned short* Kb  = Qb + ND;                   // bf16, ND
  unsigned short* VTb = Kb + ND;                   // bf16, ND (transposed V)
  unsigned short* Wb  = VTb + ND;                  // bf16, 3*D*D
  unsigned short* Op  = Wb + WBE;                  // bf16, splits*ND partial O

  auto bytes_for = [&](size_t S) {
    return (3 * ND + WBE + S * ND) * 2 + S * (size_t)NN * 8;
  };
  const int splits = (ws_size >= bytes_for(4)) ? 4 : 2;  // ws_size fixed -> same every call
  float* Mp = (float*)(Op + (size_t)splits * ND);
  float* Lp = Mp + (size_t)splits * NN;

  hipLaunchKernelGGL(prep_w, dim3(DD * DD / 2048, 1, 3), dim3(256), 0, stream,
                     Wq, Wk, Wv, Wb);
  hipLaunchKernelGGL(qkv_proj, dim3(NN / 64, 2, 3), dim3(256), 0, stream,
                     x, dx, Wb, bq, bk, bv, Qb, Kb, VTb);
  if (splits == 4) {
    hipLaunchKernelGGL(flash_attn<4>, dim3(NN / 64, 4), dim3(256), 0, stream,
                       Qb, Kb, VTb, Op, Mp, Lp);
    hipLaunchKernelGGL(combine_kernel<4>, dim3((unsigned)(ND / 2048)), dim3(256), 0, stream,
                       Op, Mp, Lp, out);
  } else {
    hipLaunchKernelGGL(flash_attn<2>, dim3(NN / 64, 2), dim3(256), 0, stream,
                       Qb, Kb, VTb, Op, Mp, Lp);
    hipLaunchKernelGGL(combine_kernel<2>, dim3((unsigned)(ND / 2048)), dim3(256), 0, stream,
                       Op, Mp, Lp, out);
  }
}

// Round 3
// 347.794 us; speedup vs baseline: 1.5694x; 1.5694x over previous
//
#include <hip/hip_runtime.h>
#include <stdint.h>

// DomainAttentionLayer: out = softmax((x Wq^T + bq)(dx Wk^T + bk)^T / sqrt(D)) (dx Wv^T + bv)
// N = M = 8192, D = 512, fp32 in/out; internal compute bf16 MFMA.
//
// Pipeline:
//   0) prep_w    : W fp32 -> bf16 (once)
//   1) qkv_proj  : bf16 GEMMs, bias fused; Q pre-scaled by log2(e)/sqrt(D); V stored VT[D][M]
//   2) flash_attn: fused online-softmax attention, split-m x SPLITS partials.
//                  D-split PV (V-frags read once per block); K AND VT staged via
//                  global_load_lds DMA (VT swizzle folded into per-lane source addrs)
//                  -> register need ~248 incl. AGPR: fits 2 blocks/CU WITHOUT spills
//                  (R2 spilled: VGPR=128 forced, 450 MB scratch traffic).
//   3) combine   : exact log-sum-exp merge of partials -> fp32 out

#define DEV __device__ __forceinline__

typedef short short8 __attribute__((ext_vector_type(8)));     // 8 bf16 (4 VGPRs) MFMA frag
typedef float floatx4 __attribute__((ext_vector_type(4)));    // MFMA accum
typedef unsigned int uintx4 __attribute__((ext_vector_type(4)));
typedef unsigned short ushortx4 __attribute__((ext_vector_type(4)));

constexpr int NN = 8192;
constexpr int MM = 8192;
constexpr int DD = 512;
constexpr float SCALE2 = 0.0637587160f;         // log2(e) / sqrt(512), folded into Q

#define NEG_INF (-__builtin_inff())

#if defined(__has_builtin)
#if __has_builtin(__builtin_amdgcn_exp2f)
#define EXP2F(x) __builtin_amdgcn_exp2f(x)
#else
#define EXP2F(x) exp2f(x)
#endif
#else
#define EXP2F(x) exp2f(x)
#endif

DEV unsigned short f2bf(float f) {              // RNE fp32 -> bf16 bits
  unsigned u = __builtin_bit_cast(unsigned, f);
  return (unsigned short)((u + 0x7FFFu + ((u >> 16) & 1u)) >> 16);
}
DEV float bf2f(unsigned short h) {
  unsigned u = ((unsigned)h) << 16;
  return __builtin_bit_cast(float, u);
}

// TBAA-safe vector ld/st (memcpy compiles to single b128/b64 with assumed alignment)
DEV short8 ld_s8(const void* p) {
  short8 v; __builtin_memcpy(&v, __builtin_assume_aligned(p, 16), 16); return v;
}
DEV uintx4 ld_u4(const void* p) {
  uintx4 v; __builtin_memcpy(&v, __builtin_assume_aligned(p, 16), 16); return v;
}
DEV void st_u4(void* p, uintx4 v) {
  __builtin_memcpy(__builtin_assume_aligned(p, 16), &v, 16);
}
DEV void st_us4(void* p, ushortx4 v) {
  __builtin_memcpy(__builtin_assume_aligned(p, 8), &v, 8);
}
DEV float4 ld_f4(const void* p) {
  float4 v; __builtin_memcpy(&v, __builtin_assume_aligned(p, 16), 16); return v;
}

DEV void async_lds16(const void* g, const void* l) {  // global -> LDS DMA, 16B/lane
  __builtin_amdgcn_global_load_lds(
      (const __attribute__((address_space(1))) unsigned int*)g,
      (__attribute__((address_space(3))) unsigned int*)l, 16, 0, 0);
}

// ---------------------------------------------------------------------------
// Kernel 0: W fp32 -> bf16, once. grid (128, 1, 3), block 256, 8 elems/thread.
// ---------------------------------------------------------------------------
__global__ void prep_w(const float* __restrict__ Wq, const float* __restrict__ Wk,
                       const float* __restrict__ Wv, unsigned short* __restrict__ Wb) {
  const int z = blockIdx.z;
  const float* src = (z == 0) ? Wq : (z == 1) ? Wk : Wv;
  unsigned short* dst = Wb + (size_t)z * DD * DD;
  size_t idx = ((size_t)blockIdx.x * 256 + threadIdx.x) * 8;
  float4 a = ld_f4(src + idx);
  float4 b = ld_f4(src + idx + 4);
  ushortx4 lo = {f2bf(a.x), f2bf(a.y), f2bf(a.z), f2bf(a.w)};
  ushortx4 hi = {f2bf(b.x), f2bf(b.y), f2bf(b.z), f2bf(b.w)};
  st_us4(dst + idx, lo);
  st_us4(dst + idx + 4, hi);
}

// ---------------------------------------------------------------------------
// Kernel 1: QKV projection. grid (128, 2, 3), block 256. Tile 64 rows x 256 cols,
// BK=64. LDS xor-swizzled (chunk ^= row&7) -> conflict-free b128 frag reads.
// z=0: Q (scaled by SCALE2) -> Qb[N][D]; z=1: K -> Kb[M][D]; z=2: V -> VTb[D][M].
// ---------------------------------------------------------------------------
__global__ __launch_bounds__(256, 2)
void qkv_proj(const float* __restrict__ x, const float* __restrict__ dx,
              const unsigned short* __restrict__ Wb,
              const float* __restrict__ bq, const float* __restrict__ bk,
              const float* __restrict__ bv,
              unsigned short* __restrict__ Qb, unsigned short* __restrict__ Kb,
              unsigned short* __restrict__ VTb) {
  const int z = blockIdx.z;
  const float* A = (z == 0) ? x : dx;
  const unsigned short* W = Wb + (size_t)z * DD * DD;
  const float* bias = (z == 0) ? bq : (z == 1) ? bk : bv;

  const int r0 = blockIdx.x * 64;
  const int c0 = blockIdx.y * 256;
  const int tid = threadIdx.x;
  const int lane = tid & 63;
  const int wave = tid >> 6;
  const int lr = lane & 15;
  const int quad = lane >> 4;

  __shared__ __align__(16) unsigned short As[64 * 64];   //  8 KB
  __shared__ __align__(16) unsigned short Ws[256 * 64];  // 32 KB

  floatx4 o[16];
#pragma unroll
  for (int i = 0; i < 16; ++i) o[i] = {0.f, 0.f, 0.f, 0.f};

  for (int k0 = 0; k0 < DD; k0 += 64) {
    // stage A tile (fp32 -> bf16): 64 rows x 64 k, 4 float4 per thread
#pragma unroll
    for (int i = 0; i < 4; ++i) {
      int idx = i * 256 + tid;
      int r = idx >> 4, c4 = idx & 15;
      float4 v = ld_f4(A + (size_t)(r0 + r) * DD + k0 + c4 * 4);
      ushortx4 pk = {f2bf(v.x), f2bf(v.y), f2bf(v.z), f2bf(v.w)};
      st_us4(&As[r * 64 + (((c4 >> 1) ^ (r & 7)) * 8) + (c4 & 1) * 4], pk);
    }
    // stage W tile (bf16, no convert): 256 rows x 64 k, 8 x 16B per thread
#pragma unroll
    for (int i = 0; i < 8; ++i) {
      int idx = i * 256 + tid;
      int r = idx >> 3, c = idx & 7;
      uintx4 v = ld_u4(W + (size_t)(c0 + r) * DD + k0 + c * 8);
      st_u4(&Ws[r * 64 + ((c ^ (r & 7)) * 8)], v);
    }
    __syncthreads();

    short8 a[2];
#pragma unroll
    for (int ks = 0; ks < 2; ++ks)
      a[ks] = ld_s8(&As[(wave * 16 + lr) * 64 + (((ks * 4 + quad) ^ (lr & 7)) * 8)]);
#pragma unroll
    for (int ct = 0; ct < 16; ++ct) {
#pragma unroll
      for (int ks = 0; ks < 2; ++ks) {
        short8 b = ld_s8(&Ws[(ct * 16 + lr) * 64 + (((ks * 4 + quad) ^ (lr & 7)) * 8)]);
        o[ct] = __builtin_amdgcn_mfma_f32_16x16x32_bf16(a[ks], b, o[ct], 0, 0, 0);
      }
    }
    __syncthreads();
  }

  // epilogue: bias (+Q scale), store. C layout: col = lr, row = quad*4 + reg.
#pragma unroll
  for (int ct = 0; ct < 16; ++ct) {
    int col = c0 + ct * 16 + lr;
    float bv_ = bias[col];
    int rowb = r0 + wave * 16 + quad * 4;
    if (z == 2) {  // VT[col][row], 4 consecutive rows -> 8B store
      ushortx4 pk = {f2bf(o[ct][0] + bv_), f2bf(o[ct][1] + bv_),
                     f2bf(o[ct][2] + bv_), f2bf(o[ct][3] + bv_)};
      st_us4(VTb + (size_t)col * MM + rowb, pk);
    } else {
      unsigned short* Outp = (z == 0) ? Qb : Kb;
      float sc = (z == 0) ? SCALE2 : 1.f;
#pragma unroll
      for (int r = 0; r < 4; ++r)
        Outp[(size_t)(rowb + r) * DD + col] = f2bf((o[ct][r] + bv_) * sc);
    }
  }
}

// ---------------------------------------------------------------------------
// Kernel 2: flash attention. 1-D grid (N/64 * SPLITS_), block 256, 2 blocks/CU.
// Block remap: split = lin & (SPLITS_-1), xt = lin >> log2(SPLITS_)  -- with
// round-robin XCD = lin%8 this pins each XCD to one split -> K/VT L2-resident.
// S phase: wave w owns q-rows [16w,16w+16) (softmax state wave-private).
// PV phase (D-split): wave w computes O[all 64 rows][cols 128w..128w+128);
// P (64x64) + alphas shared via LDS. K and VT both staged by global_load_lds
// (VT xor-swizzle folded into per-lane DMA *source* addresses).
// LDS 76,544 B. Register budget ~248 incl. AGPR -> 2 blocks/CU, no spill.
// ---------------------------------------------------------------------------
template <int SPLITS_, int LOG2S_>
__global__ __launch_bounds__(256, 2)
void flash_attn(const unsigned short* __restrict__ Qb,
                const unsigned short* __restrict__ Kb,
                const unsigned short* __restrict__ VTb,
                unsigned short* __restrict__ Opart,
                float* __restrict__ Mpart, float* __restrict__ Lpart) {
  constexpr int MT = MM / SPLITS_;
  constexpr int ITERS = MT / 64;
  const int lin = blockIdx.x;
  const int split = lin & (SPLITS_ - 1);
  const int n0 = (lin >> LOG2S_) * 64;
  const int m_begin = split * MT;

  const int tid = threadIdx.x;
  const int lane = tid & 63;
  const int wave = tid >> 6;
  const int lr = lane & 15;
  const int quad = lane >> 4;

  // sKV: K phase rows stride 520 us (1040B: DMA row + 16B pad -> frag-read banks
  // spread); VT phase rows stride 64 us with chunk^=(row&7) swizzle via DMA src.
  __shared__ __align__(16) unsigned short sKV[33280];      // 66,560 B
  __shared__ __align__(16) unsigned short sP[64 * 76];     //  9,728 B
  __shared__ float sAlpha[64];                             //    256 B

  // resident Q fragments: wave's 16 rows x 512 k (64 VGPRs), pre-scaled by SCALE2
  short8 qf[16];
  {
    const unsigned short* qptr = Qb + (size_t)(n0 + wave * 16 + lr) * DD + quad * 8;
#pragma unroll
    for (int ks = 0; ks < 16; ++ks) qf[ks] = ld_s8(qptr + ks * 32);
  }

  // VT DMA per-lane source geometry (swizzle in source, dest lane-contiguous):
  // group g = wave*16+j covers VT rows 8g..8g+7 -> LDS us [g*512, g*512+512).
  // lane i: LDS row r = 8g + (i>>3), chunk c' = i&7; source chunk c = c' ^ (r&7).
  const int vrb = lane >> 3;                                   // 0..7
  const int vcb = ((lane & 7) ^ vrb) * 8;                      // r&7 == vrb
  const unsigned short* vsrc0 = VTb + (size_t)(wave * 128 + vrb) * MM + vcb;
  unsigned short* vdst0 = &sKV[wave * 16 * 512];

  floatx4 o[32];  // [rt*8+ct] : O rows rt*16+quad*4+reg, col wave*128+ct*16+lr
#pragma unroll
  for (int i = 0; i < 32; ++i) o[i] = {0.f, 0.f, 0.f, 0.f};
  float mrow[4] = {NEG_INF, NEG_INF, NEG_INF, NEG_INF};
  float lrow[4] = {0.f, 0.f, 0.f, 0.f};

  for (int it = 0; it < ITERS; ++it) {
    const int m0 = m_begin + it * 64;

    // ---- stage K tile: one DMA per row (64 lanes x 16B = exactly 1024B row)
#pragma unroll
    for (int i = 0; i < 16; ++i) {
      const int r = wave * 16 + i;  // wave-uniform LDS dest
      async_lds16(Kb + (size_t)(m0 + r) * DD + lane * 8, &sKV[r * 520]);
    }
    __syncthreads();  // drains vmcnt -> K visible

    // ---- S = Q K^T (wave: its 16 rows x 64 cols), logits already in log2 units
    floatx4 s[4];
#pragma unroll
    for (int ct = 0; ct < 4; ++ct) s[ct] = {0.f, 0.f, 0.f, 0.f};
#pragma unroll
    for (int ks = 0; ks < 16; ++ks) {
      const unsigned short* kb = &sKV[ks * 32 + quad * 8];
#pragma unroll
      for (int ct = 0; ct < 4; ++ct) {
        short8 b = ld_s8(kb + (ct * 16 + lr) * 520);
        s[ct] = __builtin_amdgcn_mfma_f32_16x16x32_bf16(qf[ks], b, s[ct], 0, 0, 0);
      }
    }
    __syncthreads();  // all waves done with K region

    // ---- stage VT tile via DMA (swizzled source); latency hidden by softmax
    {
      const unsigned short* src = vsrc0 + m0;
#pragma unroll
      for (int j = 0; j < 16; ++j)
        async_lds16(src + (size_t)j * 8 * MM, vdst0 + j * 512);
    }

    // ---- online softmax (rows quad*4+r, cols across the 16 lanes of the quad)
    float alpha[4];
#pragma unroll
    for (int r = 0; r < 4; ++r) {
      float mx = fmaxf(fmaxf(s[0][r], s[1][r]), fmaxf(s[2][r], s[3][r]));
      mx = fmaxf(mx, __shfl_xor(mx, 1));
      mx = fmaxf(mx, __shfl_xor(mx, 2));
      mx = fmaxf(mx, __shfl_xor(mx, 4));
      mx = fmaxf(mx, __shfl_xor(mx, 8));
      float mnew = fmaxf(mrow[r], mx);
      alpha[r] = EXP2F(mrow[r] - mnew);  // first iter: exp2(-inf) = 0
      mrow[r] = mnew;
      float rs = 0.f;
#pragma unroll
      for (int ct = 0; ct < 4; ++ct) {
        float p = EXP2F(s[ct][r] - mnew);
        s[ct][r] = p;
        rs += p;
      }
      rs += __shfl_xor(rs, 1);
      rs += __shfl_xor(rs, 2);
      rs += __shfl_xor(rs, 4);
      rs += __shfl_xor(rs, 8);
      lrow[r] = lrow[r] * alpha[r] + rs;
    }
    if (lr == 0) {
#pragma unroll
      for (int r = 0; r < 4; ++r) sAlpha[wave * 16 + quad * 4 + r] = alpha[r];
    }

    // ---- P (C layout) -> shared LDS bf16 [64][76]
#pragma unroll
    for (int ct = 0; ct < 4; ++ct)
#pragma unroll
      for (int r = 0; r < 4; ++r)
        sP[(wave * 16 + quad * 4 + r) * 76 + ct * 16 + lr] = f2bf(s[ct][r]);

    __syncthreads();  // drains VT DMA; P + alphas visible

    // ---- rescale O by all-row alphas (shared, b128 loads)
    floatx4 af[4];
#pragma unroll
    for (int rt = 0; rt < 4; ++rt) {
      float4 t = ld_f4(&sAlpha[rt * 16 + quad * 4]);
      af[rt] = {t.x, t.y, t.z, t.w};
    }
    bool need = false;
#pragma unroll
    for (int rt = 0; rt < 4; ++rt)
#pragma unroll
      for (int r = 0; r < 4; ++r) need = need || (af[rt][r] < 1.f);
    if (__any(need)) {
#pragma unroll
      for (int rt = 0; rt < 4; ++rt)
#pragma unroll
        for (int ct = 0; ct < 8; ++ct)
#pragma unroll
          for (int r = 0; r < 4; ++r) o[rt * 8 + ct][r] *= af[rt][r];
    }

    // ---- O += P V (D-split): A = P rows (all 64), B = V[m][dcol], wave's 128 d-cols
#pragma unroll
    for (int ks = 0; ks < 2; ++ks) {
      short8 pa[4];
#pragma unroll
      for (int rt = 0; rt < 4; ++rt)
        pa[rt] = ld_s8(&sP[(rt * 16 + lr) * 76 + ks * 32 + quad * 8]);
#pragma unroll
      for (int ct = 0; ct < 8; ++ct) {
        const int r = wave * 128 + ct * 16 + lr;  // VT LDS row = d-col; r&7 == lr&7
        short8 b = ld_s8(&sKV[r * 64 + (((ks * 4 + quad) ^ (lr & 7)) * 8)]);
#pragma unroll
        for (int rt = 0; rt < 4; ++rt)
          o[rt * 8 + ct] = __builtin_amdgcn_mfma_f32_16x16x32_bf16(pa[rt], b,
                                                                   o[rt * 8 + ct], 0, 0, 0);
      }
    }
    __syncthreads();  // sKV/sP/sAlpha free for next iter's DMA
  }

  // ---- epilogue: unnormalized partials (D-split layout)
  unsigned short* op = Opart + (size_t)split * NN * DD;
#pragma unroll
  for (int rt = 0; rt < 4; ++rt)
#pragma unroll
    for (int ct = 0; ct < 8; ++ct) {
      int row = n0 + rt * 16 + quad * 4;
      int col = wave * 128 + ct * 16 + lr;
#pragma unroll
      for (int r = 0; r < 4; ++r)
        op[(size_t)(row + r) * DD + col] = f2bf(o[rt * 8 + ct][r]);
    }
  const int grow = n0 + wave * 16 + quad * 4;
  if (lr == 0) {
#pragma unroll
    for (int r = 0; r < 4; ++r) {
      Mpart[split * NN + grow + r] = mrow[r];
      Lpart[split * NN + grow + r] = lrow[r];
    }
  }
}

// ---------------------------------------------------------------------------
// Kernel 3: exact softmax merge of SPLITS partials. 8 elems/thread, b128 I/O.
// grid (N*D/2048), block 256.
// ---------------------------------------------------------------------------
template <int SPLITS_>
__global__ void combine_kernel(const unsigned short* __restrict__ Op,
                               const float* __restrict__ Mp,
                               const float* __restrict__ Lp,
                               float* __restrict__ out) {
  constexpr size_t NDv = (size_t)NN * DD;
  size_t base = ((size_t)blockIdx.x * 256 + threadIdx.x) * 8;
  int n = (int)(base >> 9);
  float mv[SPLITS_];
  float ms = NEG_INF;
#pragma unroll
  for (int s = 0; s < SPLITS_; ++s) {
    mv[s] = Mp[s * NN + n];
    ms = fmaxf(ms, mv[s]);
  }
  float num[8];
#pragma unroll
  for (int j = 0; j < 8; ++j) num[j] = 0.f;
  float den = 0.f;
#pragma unroll
  for (int s = 0; s < SPLITS_; ++s) {
    float w = EXP2F(mv[s] - ms);
    den += w * Lp[s * NN + n];
    uintx4 u = ld_u4(Op + s * NDv + base);
#pragma unroll
    for (int j = 0; j < 4; ++j) {
      num[2 * j]     += w * bf2f((unsigned short)(u[j] & 0xffffu));
      num[2 * j + 1] += w * bf2f((unsigned short)(u[j] >> 16));
    }
  }
  float inv = 1.f / den;
  float4 o0 = {num[0] * inv, num[1] * inv, num[2] * inv, num[3] * inv};
  float4 o1 = {num[4] * inv, num[5] * inv, num[6] * inv, num[7] * inv};
  __builtin_memcpy(__builtin_assume_aligned(out + base, 16), &o0, 16);
  __builtin_memcpy(__builtin_assume_aligned(out + base + 4, 16), &o1, 16);
}

// ---------------------------------------------------------------------------
extern "C" void kernel_launch(void* const* d_in, const int* in_sizes, int n_in,
                              void* d_out, int out_size, void* d_ws, size_t ws_size,
                              hipStream_t stream) {
  const float* x  = (const float*)d_in[0];
  const float* dx = (const float*)d_in[1];
  const float* Wq = (const float*)d_in[2];
  const float* bq = (const float*)d_in[3];
  const float* Wk = (const float*)d_in[4];
  const float* bk = (const float*)d_in[5];
  const float* Wv = (const float*)d_in[6];
  const float* bv = (const float*)d_in[7];
  float* out = (float*)d_out;

  const size_t ND = (size_t)NN * DD;          // 4,194,304
  const size_t WBE = (size_t)3 * DD * DD;     //   786,432
  unsigned short* Qb  = (unsigned short*)d_ws;     // bf16, ND (pre-scaled)
  unsigned short* Kb  = Qb + ND;                   // bf16, ND
  unsigned short* VTb = Kb + ND;                   // bf16, ND (transposed V)
  unsigned short* Wb  = VTb + ND;                  // bf16, 3*D*D
  unsigned short* Op  = Wb + WBE;                  // bf16, splits*ND partial O

  auto bytes_for = [&](size_t S) {
    return (3 * ND + WBE + S * ND) * 2 + S * (size_t)NN * 8;
  };
  const int splits = (ws_size >= bytes_for(4)) ? 4 : 2;  // ws_size fixed -> same every call
  float* Mp = (float*)(Op + (size_t)splits * ND);
  float* Lp = Mp + (size_t)splits * NN;

  hipLaunchKernelGGL(prep_w, dim3(DD * DD / 2048, 1, 3), dim3(256), 0, stream,
                     Wq, Wk, Wv, Wb);
  hipLaunchKernelGGL(qkv_proj, dim3(NN / 64, 2, 3), dim3(256), 0, stream,
                     x, dx, Wb, bq, bk, bv, Qb, Kb, VTb);
  if (splits == 4) {
    hipLaunchKernelGGL((flash_attn<4, 2>), dim3(NN / 64 * 4), dim3(256), 0, stream,
                       Qb, Kb, VTb, Op, Mp, Lp);
    hipLaunchKernelGGL(combine_kernel<4>, dim3((unsigned)(ND / 2048)), dim3(256), 0, stream,
                       Op, Mp, Lp, out);
  } else {
    hipLaunchKernelGGL((flash_attn<2, 1>), dim3(NN / 64 * 2), dim3(256), 0, stream,
                       Qb, Kb, VTb, Op, Mp, Lp);
    hipLaunchKernelGGL(combine_kernel<2>, dim3((unsigned)(ND / 2048)), dim3(256), 0, stream,
                       Op, Mp, Lp, out);
  }
}